// Round 1
// 1906.816 us; speedup vs baseline: 1.3350x; 1.3350x over previous
//
#include <hip/hip_runtime.h>

#define NPTS 8192
#define SPTS 2048
#define KS 32
#define CF 64
#define BQ 4
#define FPS_T 512
#define PPT (NPTS / FPS_T)   // 16 points per thread
#define PPT2 (PPT / 2)       // 8 point-pairs per thread
#define FPS_SHIFT 9          // log2(FPS_T)

#define OFF_GROUPED 24576                    // B*S*3
#define GROUPED_SZ  17563648                 // B*67*S*K
#define OFF_FPSIDX  (OFF_GROUPED + GROUPED_SZ)

typedef __attribute__((ext_vector_type(2))) float vf2;
typedef unsigned long long u64;

// DPP wave-64 max step helpers (VALU pipe — replaces ds_swizzle shfl chain).
// bound_ctrl=true -> out-of-bounds lanes read 0, harmless for max of nonneg values.
#define DPPMAXF(x, ctrl) do {                                                   \
    int _t = __builtin_amdgcn_mov_dpp(__float_as_int(x), (ctrl), 0xf, 0xf, true); \
    x = fmaxf((x), __int_as_float(_t));                                         \
} while (0)

#define DPPMAXU(x, ctrl) do {                                                   \
    unsigned _u = (unsigned)__builtin_amdgcn_mov_dpp((int)(x), (ctrl), 0xf, 0xf, true); \
    x = ((x) > _u) ? (x) : _u;                                                  \
} while (0)

// ---------------- FPS: one block per batch, 1 barrier per iteration ----------------
__global__ __launch_bounds__(FPS_T)
void fps_kernel(const float* __restrict__ xyz, float* __restrict__ out)
{
#pragma clang fp contract(off)
    __shared__ float sx[NPTS], sy[NPTS], sz[NPTS];   // 96 KiB coord planes (1 blk/CU)
    __shared__ u64 slots[2][8];                       // parity double-buffer, 1/wave
    const int b    = blockIdx.x;
    const int tid  = threadIdx.x;
    const int wv   = tid >> 6;
    const int lane = tid & 63;
    const float* xb = xyz + (size_t)b * (NPTS * 3);

    // SoA pair registers: component k of pair j covers points tid+512*(2j+k)
    vf2 PX[PPT2], PY[PPT2], PZ[PPT2], MD[PPT2];
#pragma unroll
    for (int j = 0; j < PPT2; ++j) {
        const int p0 = tid + FPS_T * (2 * j);
        const int p1 = p0 + FPS_T;
        const float x0 = xb[p0 * 3 + 0], y0 = xb[p0 * 3 + 1], z0 = xb[p0 * 3 + 2];
        const float x1 = xb[p1 * 3 + 0], y1 = xb[p1 * 3 + 1], z1 = xb[p1 * 3 + 2];
        sx[p0] = x0; sy[p0] = y0; sz[p0] = z0;
        sx[p1] = x1; sy[p1] = y1; sz[p1] = z1;
        vf2 vx; vx.x = x0; vx.y = x1; PX[j] = vx;
        vf2 vy; vy.x = y0; vy.y = y1; PY[j] = vy;
        vf2 vz; vz.x = z0; vz.y = z1; PZ[j] = vz;
        vf2 vm; vm.x = 1e10f; vm.y = 1e10f; MD[j] = vm;
    }
    // staged writes are ordered before first LDS coord read by the i=1 barrier

    float* newxyz = out;
    float* fpsidx = out + OFF_FPSIDX;

    // iteration 0: center = point 0
    float qx = xb[0], qy = xb[1], qz = xb[2];
    if (tid == 0) {
        fpsidx[(size_t)b * SPTS + 0] = 0.0f;
        newxyz[(size_t)b * SPTS * 3 + 0] = qx;
        newxyz[(size_t)b * SPTS * 3 + 1] = qy;
        newxyz[(size_t)b * SPTS * 3 + 2] = qz;
    }

    for (int i = 1; i < SPTS; ++i) {
        vf2 qxx; qxx.x = qx; qxx.y = qx;
        vf2 qyy; qyy.x = qy; qyy.y = qy;
        vf2 qzz; qzz.x = qz; qzz.y = qz;

        // min-dist update, fully packed; exact numpy order (dx*dx+dy*dy)+dz*dz, no fma
#pragma unroll
        for (int j = 0; j < PPT2; ++j) {
            const vf2 dx = PX[j] - qxx;
            const vf2 dy = PY[j] - qyy;
            const vf2 dz = PZ[j] - qzz;
            const vf2 d  = (dx * dx + dy * dy) + dz * dz;
            MD[j] = __builtin_elementwise_min(MD[j], d);
        }

        // packed max tree over 8 pairs, then horizontal
        vf2 m0 = __builtin_elementwise_max(MD[0], MD[1]);
        vf2 m1 = __builtin_elementwise_max(MD[2], MD[3]);
        vf2 m2 = __builtin_elementwise_max(MD[4], MD[5]);
        vf2 m3 = __builtin_elementwise_max(MD[6], MD[7]);
        m0 = __builtin_elementwise_max(m0, m1);
        m2 = __builtin_elementwise_max(m2, m3);
        m0 = __builtin_elementwise_max(m0, m2);
        const float best = fmaxf(m0.x, m0.y);

        // smallest owned j with md[j]==best (descending overwrite -> first max)
        int bj = PPT - 1;
#pragma unroll
        for (int j = PPT - 2; j >= 0; --j) {
            const float v = (j & 1) ? MD[j >> 1].y : MD[j >> 1].x;
            if (v == best) bj = j;
        }
        const int bidx = tid + (bj << FPS_SHIFT);

        // phase 1: wave max of dist via DPP (accumulates into lane 63)
        float wm = best;
        DPPMAXF(wm, 0x111);  // row_shr:1
        DPPMAXF(wm, 0x112);  // row_shr:2
        DPPMAXF(wm, 0x114);  // row_shr:4
        DPPMAXF(wm, 0x118);  // row_shr:8
        DPPMAXF(wm, 0x142);  // row_bcast:15
        DPPMAXF(wm, 0x143);  // row_bcast:31
        const float wavemax =
            __int_as_float(__builtin_amdgcn_readlane(__float_as_int(wm), 63));

        // phase 2: among exact ties, max of (8191-idx) == smallest idx
        unsigned cand = (best == wavemax) ? (unsigned)(NPTS - 1 - bidx) : 0u;
        DPPMAXU(cand, 0x111);
        DPPMAXU(cand, 0x112);
        DPPMAXU(cand, 0x114);
        DPPMAXU(cand, 0x118);
        DPPMAXU(cand, 0x142);
        DPPMAXU(cand, 0x143);
        const unsigned candmax =
            (unsigned)__builtin_amdgcn_readlane((int)cand, 63);

        // pack (dist_bits, 8191-idx): u64 max == argmax dist, tie -> smaller idx
        const u64 pk = ((u64)__float_as_uint(wavemax) << 32) | candmax;
        if (lane == 0) slots[i & 1][wv] = pk;
        __syncthreads();                      // the only barrier per iteration

        // cross-wave reduce: 8 broadcast LDS reads + 7 compares (every thread)
        u64 g = slots[i & 1][0];
#pragma unroll
        for (int w = 1; w < 8; ++w) {
            const u64 s = slots[i & 1][w];
            if (s > g) g = s;
        }
        const int widx = (NPTS - 1) - (int)(unsigned)(g & 0xffffffffull);

        // winner coords from LDS planes (uniform addr -> broadcast, ~120cy vs L2)
        qx = sx[widx]; qy = sy[widx]; qz = sz[widx];

        if (tid == 0) {
            fpsidx[(size_t)b * SPTS + i] = (float)widx;
            const size_t o = ((size_t)b * SPTS + i) * 3;
            newxyz[o + 0] = qx; newxyz[o + 1] = qy; newxyz[o + 2] = qz;
        }
    }
}

// ---------------- ball query + grouping: one wave per center ----------------
__global__ __launch_bounds__(256)
void ballgroup_kernel(const float* __restrict__ xyz, const float* __restrict__ feat,
                      float* out)
{
#pragma clang fp contract(off)
    __shared__ int idxl[4][KS];
    const int tid    = threadIdx.x;
    const int wv     = tid >> 6;
    const int lane   = tid & 63;
    const int center = blockIdx.x * 4 + wv;
    const int b      = center >> 11;          // / SPTS
    const int s      = center & (SPTS - 1);
    const float* xb  = xyz + (size_t)b * (NPTS * 3);
    const float* newxyz = out;                // written by fps_kernel earlier in stream
    const float cx = newxyz[(size_t)center * 3 + 0];
    const float cy = newxyz[(size_t)center * 3 + 1];
    const float cz = newxyz[(size_t)center * 3 + 2];

    if (lane == 0) idxl[wv][0] = 0;           // default when zero hits

    int cnt = 0;
    for (int nb = 0; nb < NPTS; nb += 64) {
        const int p = nb + lane;
        const float x = xb[p * 3 + 0];
        const float y = xb[p * 3 + 1];
        const float z = xb[p * 3 + 2];
        const float dx = cx - x, dy = cy - y, dz = cz - z;
        const float d2 = (dx * dx + dy * dy) + dz * dz;
        // f32 'd2 <= 0.04f' == numpy 'f32 d2 < float64(0.2*0.2)'
        const bool in = (d2 <= 0.04f);
        const unsigned long long mk = __ballot(in);
        if (in) {
            const int pos = cnt + __popcll(mk & ((1ull << lane) - 1ull));
            if (pos < KS) idxl[wv][pos] = p;
        }
        cnt += (int)__popcll(mk);
        if (cnt >= KS) break;                 // cnt is wave-uniform
    }
    const int cc = cnt < KS ? cnt : KS;

    // pad short lists with first hit (or 0), write padded list back
    int myidx = 0;
    if (lane < KS) {
        myidx = (lane < cc) ? idxl[wv][lane] : idxl[wv][0];
        idxl[wv][lane] = myidx;
    }

    float* grouped = out + OFF_GROUPED;
    const size_t chstride = (size_t)SPTS * KS;                    // 65536
    const size_t base67   = (size_t)b * 67 * chstride + (size_t)s * KS;

    // channels 0..2: recentered coords (point - center)
    if (lane < KS) {
        const float gx = xb[(size_t)myidx * 3 + 0] - cx;
        const float gy = xb[(size_t)myidx * 3 + 1] - cy;
        const float gz = xb[(size_t)myidx * 3 + 2] - cz;
        grouped[base67 + 0 * chstride + lane] = gx;
        grouped[base67 + 1 * chstride + lane] = gy;
        grouped[base67 + 2 * chstride + lane] = gz;
    }

    // channels 3..66: feature gather; lanes = (k, c-half)
    const int k    = lane & (KS - 1);
    const int half = lane >> 5;
    const int gi   = idxl[wv][k];
    const float* fb = feat + (size_t)b * CF * NPTS;
    const size_t obase = base67 + 3 * chstride + (size_t)k;
#pragma unroll 8
    for (int c0 = 0; c0 < 32; ++c0) {
        const int c = c0 * 2 + half;
        grouped[obase + (size_t)c * chstride] = fb[(size_t)c * NPTS + gi];
    }
}

extern "C" void kernel_launch(void* const* d_in, const int* in_sizes, int n_in,
                              void* d_out, int out_size, void* d_ws, size_t ws_size,
                              hipStream_t stream) {
    const float* xyz  = (const float*)d_in[0];
    const float* feat = (const float*)d_in[1];
    float* out = (float*)d_out;
    fps_kernel<<<dim3(BQ), dim3(FPS_T), 0, stream>>>(xyz, out);
    ballgroup_kernel<<<dim3((BQ * SPTS) / 4), dim3(256), 0, stream>>>(xyz, feat, out);
}